// Round 5
// baseline (620.137 us; speedup 1.0000x reference)
//
#include <hip/hip_runtime.h>
#include <math.h>

// Problem constants
#define HID   4096
#define SLOTS 8
#define HEADS 8
#define BD    512
#define HD    64
#define BB    4
#define SS    4096
#define R64   64          // HEADS*SLOTS rows; r = h*8 + n

typedef __attribute__((ext_vector_type(8))) short bf16x8;
typedef __attribute__((ext_vector_type(4))) float f32x4;

// fp32 -> bf16 bits, round-to-nearest-even (inputs finite)
__device__ __forceinline__ unsigned short f2bf(float x) {
  unsigned int u = __builtin_bit_cast(unsigned int, x);
  return (unsigned short)((u + 0x7fffu + ((u >> 16) & 1u)) >> 16);
}
__device__ __forceinline__ float bf2f(unsigned short h) {
  unsigned int u = ((unsigned int)h) << 16;
  return __builtin_bit_cast(float, u);
}

// ---- 1: Q = ms @ Wq^T  (8x512). One wave per output element.
__global__ void q_kernel(const float* __restrict__ ms, const float* __restrict__ Wq,
                         float* __restrict__ Q) {
  int w = (blockIdx.x * blockDim.x + threadIdx.x) >> 6;
  int lane = threadIdx.x & 63;
  if (w >= SLOTS * BD) return;
  int n = w >> 9, o = w & (BD - 1);
  const float* a = ms + n * HID;
  const float* b = Wq + (size_t)o * HID;
  float acc = 0.f;
  for (int i = lane; i < HID; i += 64) acc = fmaf(a[i], b[i], acc);
  #pragma unroll
  for (int off = 32; off; off >>= 1) acc += __shfl_down(acc, off, 64);
  if (lane == 0) Q[w] = acc;
}

// ---- 2: QW[r][i] = 0.125 * sum_d Q[n][h*64+d] * Wk[h*64+d][i],  r = h*8+n  (bf16 out)
__global__ void qw_kernel(const float* __restrict__ Q, const float* __restrict__ Wk,
                          unsigned short* __restrict__ QW) {
  int idx = blockIdx.x * blockDim.x + threadIdx.x;   // 64*4096
  int r = idx >> 12, i = idx & (HID - 1);
  int h = r >> 3, n = r & 7;
  const float* q  = Q + n * BD + h * HD;
  const float* wk = Wk + (size_t)(h * HD) * HID + i;
  float acc = 0.f;
  #pragma unroll 8
  for (int d = 0; d < HD; ++d) acc = fmaf(q[d], wk[(size_t)d * HID], acc);
  QW[idx] = f2bf(acc * 0.125f);
}

// ---- 3: scores + exp + denom partials, full K per block, NO barriers in K-loop.
// A = QW rows (bf16, L2-hot, direct b128 frag loads); B = hs fp32 rows, cvt in-register.
// grid (64 stile, 4 b), 256 thr. Block: 64 r x 64 s, K=4096.
// Writes attn[b][r][s] = bf16(mask ? exp(score) : 0) and denomp[b][r][stile] = sum_s e.
__global__ __launch_bounds__(256) void scores_mfma(const float* __restrict__ hs,
                                                   const unsigned short* __restrict__ QW,
                                                   const int* __restrict__ mask,
                                                   unsigned short* __restrict__ attn,
                                                   float* __restrict__ denomp) {
  __shared__ float denw[256];
  const int stile = blockIdx.x, b = blockIdx.y;
  const int tid = threadIdx.x;
  const int wv = tid >> 6, lane = tid & 63;
  const int quad = lane >> 4, l16 = lane & 15;
  const int s = stile * 64 + wv * 16 + l16;
  const float* bp = hs + ((size_t)b * SS + s) * HID + quad * 8;
  const unsigned short* ap = QW + (size_t)l16 * HID + quad * 8;

  f32x4 acc[4] = {};
  // 3-deep pipeline: cur, nxt in regs; fut loaded each iter
  float4 cb0 = *(const float4*)(bp),      cb1 = *(const float4*)(bp + 4);
  uint4  ca0 = *(const uint4*)(ap);
  uint4  ca1 = *(const uint4*)(ap + 16 * HID);
  uint4  ca2 = *(const uint4*)(ap + 32 * HID);
  uint4  ca3 = *(const uint4*)(ap + 48 * HID);
  float4 nb0 = *(const float4*)(bp + 32), nb1 = *(const float4*)(bp + 36);
  uint4  na0 = *(const uint4*)(ap + 32);
  uint4  na1 = *(const uint4*)(ap + 16 * HID + 32);
  uint4  na2 = *(const uint4*)(ap + 32 * HID + 32);
  uint4  na3 = *(const uint4*)(ap + 48 * HID + 32);

  for (int k0 = 0; k0 < 4096; k0 += 32) {
    float4 fb0, fb1; uint4 fa0, fa1, fa2, fa3;
    if (k0 + 64 < 4096) {
      fb0 = *(const float4*)(bp + k0 + 64);
      fb1 = *(const float4*)(bp + k0 + 68);
      fa0 = *(const uint4*)(ap + k0 + 64);
      fa1 = *(const uint4*)(ap + 16 * HID + k0 + 64);
      fa2 = *(const uint4*)(ap + 32 * HID + k0 + 64);
      fa3 = *(const uint4*)(ap + 48 * HID + k0 + 64);
    } else {
      fb0 = nb0; fb1 = nb1; fa0 = na0; fa1 = na1; fa2 = na2; fa3 = na3;
    }
    float f[8] = {cb0.x, cb0.y, cb0.z, cb0.w, cb1.x, cb1.y, cb1.z, cb1.w};
    union { unsigned short us[8]; bf16x8 v; } ub;
    #pragma unroll
    for (int j = 0; j < 8; ++j) ub.us[j] = f2bf(f[j]);
    acc[0] = __builtin_amdgcn_mfma_f32_16x16x32_bf16(__builtin_bit_cast(bf16x8, ca0), ub.v, acc[0], 0, 0, 0);
    acc[1] = __builtin_amdgcn_mfma_f32_16x16x32_bf16(__builtin_bit_cast(bf16x8, ca1), ub.v, acc[1], 0, 0, 0);
    acc[2] = __builtin_amdgcn_mfma_f32_16x16x32_bf16(__builtin_bit_cast(bf16x8, ca2), ub.v, acc[2], 0, 0, 0);
    acc[3] = __builtin_amdgcn_mfma_f32_16x16x32_bf16(__builtin_bit_cast(bf16x8, ca3), ub.v, acc[3], 0, 0, 0);
    cb0 = nb0; cb1 = nb1; ca0 = na0; ca1 = na1; ca2 = na2; ca3 = na3;
    nb0 = fb0; nb1 = fb1; na0 = fa0; na1 = fa1; na2 = fa2; na3 = fa3;
  }

  // Epilogue: C layout col(n=s)=l16 (lane's fixed s), row(m=r)=mt*16+quad*4+reg.
  const int mk = mask[b * SS + s];
  float er[16];
  #pragma unroll
  for (int mt = 0; mt < 4; ++mt)
    #pragma unroll
    for (int j = 0; j < 4; ++j) {
      float e = mk ? __expf(acc[mt][j]) : 0.f;
      unsigned short h = f2bf(e);
      attn[((size_t)b * R64 + mt * 16 + quad * 4 + j) * SS + s] = h;
      er[mt * 4 + j] = bf2f(h);    // denom over ROUNDED weights -> weights sum to 1
    }
  #pragma unroll
  for (int v = 0; v < 16; ++v) {
    float e = er[v];
    #pragma unroll
    for (int xm = 1; xm < 16; xm <<= 1) e += __shfl_xor(e, xm, 64);
    er[v] = e;
  }
  if (l16 == 0) {
    #pragma unroll
    for (int mt = 0; mt < 4; ++mt)
      #pragma unroll
      for (int j = 0; j < 4; ++j)
        denw[wv * 64 + mt * 16 + quad * 4 + j] = er[mt * 4 + j];
  }
  __syncthreads();
  if (tid < 64)
    denomp[((size_t)b * R64 + tid) * 64 + stile] =
        denw[tid] + denw[64 + tid] + denw[128 + tid] + denw[192 + tid];
}

// ---- 4: invden[b*64+r] = 1 / sum_stile denomp
__global__ void invden_kernel(const float* __restrict__ denomp, float* __restrict__ invden) {
  int t = threadIdx.x;   // 256
  const float4* p = (const float4*)(denomp + (size_t)t * 64);
  float s = 0.f;
  #pragma unroll
  for (int j = 0; j < 16; ++j) { float4 v = p[j]; s += v.x + v.y + v.z + v.w; }
  invden[t] = 1.f / s;
}

// ---- 5: partial ctx cp[ss][b][r][i] = sum_{s-slice} attn[b][r][s]*hs[b][s][i]
// A = attn rows (bf16, L2-hot, b128 frags); B = hs columns (8 scalar fp32 loads/frag,
// 16-lane x 4B = 64-B coalesced segments). No barriers. grid (64 itile, 4 ss, 4 b).
__global__ __launch_bounds__(256) void ctx_mfma(const unsigned short* __restrict__ attn,
                                                const float* __restrict__ hs,
                                                float* __restrict__ cp) {
  const int itile = blockIdx.x, ssb = blockIdx.y, b = blockIdx.z;
  const int tid = threadIdx.x;
  const int wv = tid >> 6, lane = tid & 63;
  const int quad = lane >> 4, l16 = lane & 15;
  const int i = itile * 64 + wv * 16 + l16;
  const unsigned short* ap = attn + ((size_t)b * R64 + l16) * SS + ssb * 1024 + quad * 8;
  const float* bp = hs + ((size_t)(b * SS) + ssb * 1024 + quad * 8) * HID + i;

  f32x4 acc[4] = {};
  uint4 ca[4], na[4];
  float cb[8], nb[8];
  #pragma unroll
  for (int mt = 0; mt < 4; ++mt) ca[mt] = *(const uint4*)(ap + mt * 16 * SS);
  #pragma unroll
  for (int j = 0; j < 8; ++j) cb[j] = bp[j * HID];
  #pragma unroll
  for (int mt = 0; mt < 4; ++mt) na[mt] = *(const uint4*)(ap + mt * 16 * SS + 32);
  #pragma unroll
  for (int j = 0; j < 8; ++j) nb[j] = bp[(32 + j) * HID];

  for (int s0 = 0; s0 < 1024; s0 += 32) {
    uint4 fa[4]; float fb[8];
    if (s0 + 64 < 1024) {
      #pragma unroll
      for (int mt = 0; mt < 4; ++mt) fa[mt] = *(const uint4*)(ap + mt * 16 * SS + s0 + 64);
      #pragma unroll
      for (int j = 0; j < 8; ++j) fb[j] = bp[(s0 + 64 + j) * HID];
    } else {
      #pragma unroll
      for (int mt = 0; mt < 4; ++mt) fa[mt] = na[mt];
      #pragma unroll
      for (int j = 0; j < 8; ++j) fb[j] = nb[j];
    }
    union { unsigned short us[8]; bf16x8 v; } ub;
    #pragma unroll
    for (int j = 0; j < 8; ++j) ub.us[j] = f2bf(cb[j]);
    #pragma unroll
    for (int mt = 0; mt < 4; ++mt)
      acc[mt] = __builtin_amdgcn_mfma_f32_16x16x32_bf16(__builtin_bit_cast(bf16x8, ca[mt]), ub.v, acc[mt], 0, 0, 0);
    #pragma unroll
    for (int mt = 0; mt < 4; ++mt) { ca[mt] = na[mt]; na[mt] = fa[mt]; }
    #pragma unroll
    for (int j = 0; j < 8; ++j) { cb[j] = nb[j]; nb[j] = fb[j]; }
  }
  // C layout: col(n=i)=l16, row(m=r)=mt*16+quad*4+reg
  #pragma unroll
  for (int mt = 0; mt < 4; ++mt)
    #pragma unroll
    for (int j = 0; j < 4; ++j)
      cp[(((size_t)ssb * BB + b) * R64 + mt * 16 + quad * 4 + j) * HID + i] = acc[mt][j];
}

// ---- 6: ctx[b][r][i] = (sum_ss cp) * invden[b*64+r]
__global__ void ctx_reduce(const float* __restrict__ cp, const float* __restrict__ invden,
                           float* __restrict__ ctx) {
  int idx = blockIdx.x * 256 + threadIdx.x;   // 1M
  const size_t n = (size_t)BB * R64 * HID;
  float v = cp[idx] + cp[idx + n] + cp[idx + 2 * n] + cp[idx + 3 * n];
  ctx[idx] = v * invden[idx >> 12];
}

// ---- 7: out[b][n][h*64+d] = sum_i ctx[b][h*8+n][i] * Wv[h*64+d][i]
__global__ void out_kernel(const float* __restrict__ ctx, const float* __restrict__ Wv,
                           float* __restrict__ out) {
  int w = (blockIdx.x * blockDim.x + threadIdx.x) >> 6;
  int lane = threadIdx.x & 63;
  if (w >= BB * SLOTS * BD) return;   // 16384
  int b = w >> 12, n = (w >> 9) & 7, hd = w & 511, h = hd >> 6;
  const float* c  = ctx + ((size_t)b * R64 + h * 8 + n) * HID;
  const float* wv = Wv + (size_t)hd * HID;
  float acc = 0.f;
  for (int i = lane; i < HID; i += 64) acc = fmaf(c[i], wv[i], acc);
  #pragma unroll
  for (int off = 32; off; off >>= 1) acc += __shfl_down(acc, off, 64);
  if (lane == 0) out[w] = acc;
}

// ---- 8: y[b][n][o] = sum_d out[b][n][d] * Wo[o][d]
__global__ void final_kernel(const float* __restrict__ out, const float* __restrict__ Wo,
                             float* __restrict__ y) {
  int w = (blockIdx.x * blockDim.x + threadIdx.x) >> 6;
  int lane = threadIdx.x & 63;
  if (w >= BB * SLOTS * HID) return;  // 131072
  int bn = w >> 12, o = w & 4095;
  const float* orow = out + bn * BD;
  const float* wo = Wo + (size_t)o * BD;
  float acc = 0.f;
  #pragma unroll
  for (int d = lane; d < BD; d += 64) acc = fmaf(orow[d], wo[d], acc);
  #pragma unroll
  for (int off = 32; off; off >>= 1) acc += __shfl_down(acc, off, 64);
  if (lane == 0) y[w] = acc;
}

extern "C" void kernel_launch(void* const* d_in, const int* in_sizes, int n_in,
                              void* d_out, int out_size, void* d_ws, size_t ws_size,
                              hipStream_t stream) {
  const float* hs   = (const float*)d_in[0];
  const int*   mask = (const int*)d_in[1];
  const float* ms   = (const float*)d_in[2];
  const float* Wq   = (const float*)d_in[3];
  const float* Wk   = (const float*)d_in[4];
  const float* Wv   = (const float*)d_in[5];
  const float* Wo   = (const float*)d_in[6];

  // Workspace layout (~23 MB)
  char* ws = (char*)d_ws;
  float*          Q      = (float*)ws;          ws += 4096 * 4;                        // 16 KB
  unsigned short* QW     = (unsigned short*)ws; ws += (size_t)R64 * HID * 2;           // 512 KB
  unsigned short* attn   = (unsigned short*)ws; ws += (size_t)BB * R64 * SS * 2;       // 2 MB
  float*          denomp = (float*)ws;          ws += 256 * 64 * 4;                    // 64 KB
  float*          invden = (float*)ws;          ws += 256 * 4 + 3072;                  // pad
  float*          cp     = (float*)ws;          ws += (size_t)4 * BB * R64 * HID * 4;  // 16 MB
  float*          ctx    = (float*)ws;          ws += (size_t)BB * R64 * HID * 4;      // 4 MB
  float*          out    = (float*)ws;                                                 // 64 KB

  q_kernel<<<dim3(1024), 256, 0, stream>>>(ms, Wq, Q);
  qw_kernel<<<dim3((R64 * HID) / 256), 256, 0, stream>>>(Q, Wk, QW);
  scores_mfma<<<dim3(64, 4), 256, 0, stream>>>(hs, QW, mask, attn, denomp);
  invden_kernel<<<dim3(1), 256, 0, stream>>>(denomp, invden);
  ctx_mfma<<<dim3(64, 4, 4), 256, 0, stream>>>(attn, hs, cp);
  ctx_reduce<<<dim3(4096), 256, 0, stream>>>(cp, invden, ctx);
  out_kernel<<<dim3(4096), 256, 0, stream>>>(ctx, Wv, out);
  final_kernel<<<dim3(32768), 256, 0, stream>>>(out, Wo, (float*)d_out);
}